// Round 1
// baseline (6595.811 us; speedup 1.0000x reference)
//
#include <hip/hip_runtime.h>
#include <hip/hip_bf16.h>
#include <math.h>

#define B_SZ     2
#define LSEQ     2048
#define DMODEL   2048
#define INTER    4096
#define HEADS    64
#define PDIM     64
#define NSTATE   128
#define CONV_DIM 4352   /* INTER + 2*128 */
#define EPS      1e-5f

// ---------------------------------------------------------------------------
// Generic fp32 GEMM: C[M,N] = A[M,K] @ W[K,N], all row-major.
// Tile: BM=128, BN=64, BK=16; 256 threads; 8x4 acc per thread.
// A staged k-major (Asm[k][m]) so inner reads are broadcast b128.
// Requires M%128==0, N%64==0, K%16==0 (true for all call sites).
// ---------------------------------------------------------------------------
__global__ __launch_bounds__(256) void gemm_f32(
    const float* __restrict__ A, const float* __restrict__ W,
    float* __restrict__ C, int M, int Nn, int Kd)
{
    __shared__ float Asm[16][128];
    __shared__ float Ws[16][64];

    const int tid = threadIdx.x;
    const int tx  = tid & 15;        // n sub-tile
    const int ty  = tid >> 4;        // m sub-tile (0..15)
    const int m0  = blockIdx.y * 128;
    const int n0  = blockIdx.x * 64;

    const int arow = tid >> 1;            // 0..127
    const int acol = (tid & 1) * 8;       // 0 or 8
    const int wrow = tid >> 4;            // 0..15
    const int wcol = (tid & 15) * 4;

    const float* Aptr = A + (size_t)(m0 + arow) * Kd + acol;
    const float* Wptr = W + (size_t)wrow * Nn + n0 + wcol;

    float acc[8][4];
    #pragma unroll
    for (int i = 0; i < 8; ++i)
        #pragma unroll
        for (int j = 0; j < 4; ++j) acc[i][j] = 0.f;

    for (int k0 = 0; k0 < Kd; k0 += 16) {
        float4 av0 = *(const float4*)(Aptr + k0);
        float4 av1 = *(const float4*)(Aptr + k0 + 4);
        float4 wv  = *(const float4*)(Wptr + (size_t)k0 * Nn);

        __syncthreads();   // protect previous iteration's LDS reads
        Asm[acol + 0][arow] = av0.x;
        Asm[acol + 1][arow] = av0.y;
        Asm[acol + 2][arow] = av0.z;
        Asm[acol + 3][arow] = av0.w;
        Asm[acol + 4][arow] = av1.x;
        Asm[acol + 5][arow] = av1.y;
        Asm[acol + 6][arow] = av1.z;
        Asm[acol + 7][arow] = av1.w;
        *(float4*)&Ws[wrow][wcol] = wv;
        __syncthreads();

        #pragma unroll
        for (int k = 0; k < 16; ++k) {
            float4 a0  = *(const float4*)&Asm[k][ty * 8];
            float4 a1  = *(const float4*)&Asm[k][ty * 8 + 4];
            float4 wv2 = *(const float4*)&Ws[k][tx * 4];
            float av[8] = {a0.x, a0.y, a0.z, a0.w, a1.x, a1.y, a1.z, a1.w};
            #pragma unroll
            for (int i = 0; i < 8; ++i) {
                acc[i][0] = fmaf(av[i], wv2.x, acc[i][0]);
                acc[i][1] = fmaf(av[i], wv2.y, acc[i][1]);
                acc[i][2] = fmaf(av[i], wv2.z, acc[i][2]);
                acc[i][3] = fmaf(av[i], wv2.w, acc[i][3]);
            }
        }
    }

    #pragma unroll
    for (int i = 0; i < 8; ++i) {
        float4 o = make_float4(acc[i][0], acc[i][1], acc[i][2], acc[i][3]);
        *(float4*)&C[(size_t)(m0 + ty * 8 + i) * Nn + n0 + tx * 4] = o;
    }
}

// ---------------------------------------------------------------------------
// dt = softplus_thresh(dt_mm + dt_bias); dA = exp(dt * (-exp(A_log)))
// In-place over the dt GEMM output.
// ---------------------------------------------------------------------------
__global__ void dt_kernel(float* __restrict__ dtio, float* __restrict__ dAo,
                          const float* __restrict__ dt_bias,
                          const float* __restrict__ A_log, int n)
{
    int i = blockIdx.x * 256 + threadIdx.x;
    if (i >= n) return;
    int h = i & (HEADS - 1);
    float x   = dtio[i] + dt_bias[h];
    float dtv = (x < 10.f) ? log1pf(expf(x)) : x;
    dtio[i] = dtv;
    dAo[i]  = expf(-dtv * expf(A_log[h]));
}

// ---------------------------------------------------------------------------
// Causal depthwise conv1d (K=4) + bias + silu.
// grid: (CONV_DIM/256=17, B*L=8192)
// ---------------------------------------------------------------------------
__global__ void conv_kernel(const float* __restrict__ xin,
                            const float* __restrict__ cw,
                            const float* __restrict__ cb,
                            float* __restrict__ xout)
{
    int c  = blockIdx.x * 256 + threadIdx.x;   // < 4352 exactly
    int bt = blockIdx.y;                       // b*L + t
    int t  = bt & (LSEQ - 1);
    size_t i = (size_t)bt * CONV_DIM + c;
    float4 w = *(const float4*)(cw + (size_t)c * 4);  // [w0,w1,w2,w3]
    float acc = cb[c];
    acc = fmaf(xin[i], w.w, acc);                                // x[t]   * w3
    if (t >= 1) acc = fmaf(xin[i - CONV_DIM],     w.z, acc);     // x[t-1] * w2
    if (t >= 2) acc = fmaf(xin[i - 2 * CONV_DIM], w.y, acc);     // x[t-2] * w1
    if (t >= 3) acc = fmaf(xin[i - 3 * CONV_DIM], w.x, acc);     // x[t-3] * w0
    xout[i] = acc / (1.f + expf(-acc));                          // silu
}

// ---------------------------------------------------------------------------
// Sequential SSM scan. One wave per (b, h, p-quarter): 512 blocks x 64 thr.
// Lane: pl = lane>>2 (16 p rows), q = lane&3 (n quarter, 32 n each).
// State st[32] in registers. No LDS, no barriers; B/C read from global (L2).
// y[b,t,h*64+p] = sum_n state*C + D[h]*x
// ---------------------------------------------------------------------------
__global__ __launch_bounds__(64) void scan_kernel(
    const float* __restrict__ xc,   // [B,L,CONV_DIM] post-conv
    const float* __restrict__ dt,   // [B,L,H]
    const float* __restrict__ dA,   // [B,L,H]
    const float* __restrict__ Dvec, // [H]
    float* __restrict__ y)          // [B,L,INTER]
{
    const int blk = blockIdx.x;
    const int b   = blk >> 8;
    const int h   = (blk >> 2) & 63;
    const int p0  = (blk & 3) << 4;
    const int lane = threadIdx.x;
    const int pl = lane >> 2;
    const int q  = lane & 3;
    const int p  = p0 + pl;

    float st[32];
    #pragma unroll
    for (int j = 0; j < 32; ++j) st[j] = 0.f;

    const float Dh = Dvec[h];
    const float* Bp  = xc + (size_t)b * LSEQ * CONV_DIM + INTER + q * 32;
    const float* Cp  = Bp + NSTATE;
    const float* xp  = xc + (size_t)b * LSEQ * CONV_DIM + h * 64 + p;
    const float* dtp = dt + (size_t)b * LSEQ * HEADS + h;
    const float* dAp = dA + (size_t)b * LSEQ * HEADS + h;
    float*       yp  = y  + (size_t)b * LSEQ * INTER + h * 64 + p;

    for (int t = 0; t < LSEQ; ++t) {
        float4 Bv[8], Cv[8];
        #pragma unroll
        for (int u = 0; u < 8; ++u) {
            Bv[u] = *(const float4*)(Bp + u * 4);
            Cv[u] = *(const float4*)(Cp + u * 4);
        }
        float xv  = *xp;
        float dtv = *dtp;
        float dav = *dAp;
        float dtx = dtv * xv;

        const float* bb = (const float*)Bv;
        const float* cc = (const float*)Cv;
        float acc = 0.f;
        #pragma unroll
        for (int j = 0; j < 32; ++j) {
            st[j] = fmaf(dav, st[j], dtx * bb[j]);
            acc   = fmaf(st[j], cc[j], acc);
        }
        acc += __shfl_xor(acc, 1);
        acc += __shfl_xor(acc, 2);
        if (q == 0) *yp = acc + Dh * xv;

        Bp  += CONV_DIM; Cp += CONV_DIM; xp += CONV_DIM;
        dtp += HEADS;    dAp += HEADS;
        yp  += INTER;
    }
}

// ---------------------------------------------------------------------------
// Gated RMSNorm (G=1: full 4096 row). normed written in-place over gate.
// One block (256 thr) per row; 16 elems/thread.
// ---------------------------------------------------------------------------
__global__ __launch_bounds__(256) void norm_kernel(
    const float* __restrict__ y, float* __restrict__ gate,
    const float* __restrict__ w)
{
    const int row = blockIdx.x;
    const float* yr = y    + (size_t)row * INTER;
    float*       gr = gate + (size_t)row * INTER;
    const int tid = threadIdx.x;

    float v[16];
    float ss = 0.f;
    #pragma unroll
    for (int i = 0; i < 16; ++i) {
        int idx = tid + i * 256;
        float hv = yr[idx];
        float g  = gr[idx];
        float sg = g / (1.f + expf(-g));   // silu(g)
        float val = hv * sg;
        v[i] = val;
        ss = fmaf(val, val, ss);
    }
    #pragma unroll
    for (int o = 32; o > 0; o >>= 1) ss += __shfl_xor(ss, o);
    __shared__ float part[4];
    if ((tid & 63) == 0) part[tid >> 6] = ss;
    __syncthreads();
    float tot  = part[0] + part[1] + part[2] + part[3];
    float rinv = rsqrtf(tot * (1.f / INTER) + EPS);
    #pragma unroll
    for (int i = 0; i < 16; ++i) {
        int idx = tid + i * 256;
        gr[idx] = w[idx] * v[i] * rinv;
    }
}

// ---------------------------------------------------------------------------
extern "C" void kernel_launch(void* const* d_in, const int* in_sizes, int n_in,
                              void* d_out, int out_size, void* d_ws, size_t ws_size,
                              hipStream_t stream)
{
    const float* hs      = (const float*)d_in[0];
    const float* W_z     = (const float*)d_in[1];
    const float* W_xBC   = (const float*)d_in[2];
    const float* W_dt    = (const float*)d_in[3];
    const float* conv_w  = (const float*)d_in[4];
    const float* conv_b  = (const float*)d_in[5];
    const float* dt_bias = (const float*)d_in[6];
    const float* A_log   = (const float*)d_in[7];
    const float* Dv      = (const float*)d_in[8];
    const float* norm_w  = (const float*)d_in[9];
    const float* W_out   = (const float*)d_in[10];
    float* out = (float*)d_out;
    float* ws  = (float*)d_ws;

    // workspace layout (floats):
    float* gate  = ws;                 // 4096*4096        = 16777216
    float* xpre  = ws + 16777216;      // 4096*4352        = 17825792 (reused as y)
    float* xconv = ws + 34603008;      // 4096*4352        = 17825792
    float* dtb   = ws + 52428800;      // 4096*64          = 262144
    float* dAb   = ws + 52690944;      // 4096*64          = 262144
    float* yb    = xpre;               // alias: xpre dead after conv

    const int M = B_SZ * LSEQ;         // 4096

    // 1-3: input projections
    gemm_f32<<<dim3(INTER / 64,    M / 128), 256, 0, stream>>>(hs, W_z,   gate, M, INTER,    DMODEL);
    gemm_f32<<<dim3(CONV_DIM / 64, M / 128), 256, 0, stream>>>(hs, W_xBC, xpre, M, CONV_DIM, DMODEL);
    gemm_f32<<<dim3(HEADS / 64,    M / 128), 256, 0, stream>>>(hs, W_dt,  dtb,  M, HEADS,    DMODEL);

    // 4: dt softplus + dA
    dt_kernel<<<(M * HEADS + 255) / 256, 256, 0, stream>>>(dtb, dAb, dt_bias, A_log, M * HEADS);

    // 5: causal depthwise conv + silu
    conv_kernel<<<dim3(CONV_DIM / 256, M), 256, 0, stream>>>(xpre, conv_w, conv_b, xconv);

    // 6: sequential scan
    scan_kernel<<<B_SZ * HEADS * 4, 64, 0, stream>>>(xconv, dtb, dAb, Dv, yb);

    // 7: gated RMSNorm (normed in-place over gate)
    norm_kernel<<<M, 256, 0, stream>>>(yb, gate, norm_w);

    // 8: output projection -> d_out
    gemm_f32<<<dim3(DMODEL / 64, M / 128), 256, 0, stream>>>(gate, W_out, out, M, DMODEL, INTER);
}

// Round 2
// 3719.181 us; speedup vs baseline: 1.7735x; 1.7735x over previous
//
#include <hip/hip_runtime.h>
#include <hip/hip_bf16.h>
#include <math.h>

#define B_SZ     2
#define LSEQ     2048
#define DMODEL   2048
#define INTER    4096
#define HEADS    64
#define PDIM     64
#define NSTATE   128
#define CONV_DIM 4352   /* INTER + 2*128 */
#define EPS      1e-5f
#define TCH      32     /* scan time-chunk */

// ---------------------------------------------------------------------------
// Generic fp32 GEMM: C[M,N] = A[M,K] @ W[K,N], all row-major.
// Tile: BM=128, BN=64, BK=16; 256 threads; 8x4 acc per thread.
// ---------------------------------------------------------------------------
__global__ __launch_bounds__(256) void gemm_f32(
    const float* __restrict__ A, const float* __restrict__ W,
    float* __restrict__ C, int M, int Nn, int Kd)
{
    __shared__ float Asm[16][128];
    __shared__ float Ws[16][64];

    const int tid = threadIdx.x;
    const int tx  = tid & 15;
    const int ty  = tid >> 4;
    const int m0  = blockIdx.y * 128;
    const int n0  = blockIdx.x * 64;

    const int arow = tid >> 1;
    const int acol = (tid & 1) * 8;
    const int wrow = tid >> 4;
    const int wcol = (tid & 15) * 4;

    const float* Aptr = A + (size_t)(m0 + arow) * Kd + acol;
    const float* Wptr = W + (size_t)wrow * Nn + n0 + wcol;

    float acc[8][4];
    #pragma unroll
    for (int i = 0; i < 8; ++i)
        #pragma unroll
        for (int j = 0; j < 4; ++j) acc[i][j] = 0.f;

    for (int k0 = 0; k0 < Kd; k0 += 16) {
        float4 av0 = *(const float4*)(Aptr + k0);
        float4 av1 = *(const float4*)(Aptr + k0 + 4);
        float4 wv  = *(const float4*)(Wptr + (size_t)k0 * Nn);

        __syncthreads();
        Asm[acol + 0][arow] = av0.x;
        Asm[acol + 1][arow] = av0.y;
        Asm[acol + 2][arow] = av0.z;
        Asm[acol + 3][arow] = av0.w;
        Asm[acol + 4][arow] = av1.x;
        Asm[acol + 5][arow] = av1.y;
        Asm[acol + 6][arow] = av1.z;
        Asm[acol + 7][arow] = av1.w;
        *(float4*)&Ws[wrow][wcol] = wv;
        __syncthreads();

        #pragma unroll
        for (int k = 0; k < 16; ++k) {
            float4 a0  = *(const float4*)&Asm[k][ty * 8];
            float4 a1  = *(const float4*)&Asm[k][ty * 8 + 4];
            float4 wv2 = *(const float4*)&Ws[k][tx * 4];
            float av[8] = {a0.x, a0.y, a0.z, a0.w, a1.x, a1.y, a1.z, a1.w};
            #pragma unroll
            for (int i = 0; i < 8; ++i) {
                acc[i][0] = fmaf(av[i], wv2.x, acc[i][0]);
                acc[i][1] = fmaf(av[i], wv2.y, acc[i][1]);
                acc[i][2] = fmaf(av[i], wv2.z, acc[i][2]);
                acc[i][3] = fmaf(av[i], wv2.w, acc[i][3]);
            }
        }
    }

    #pragma unroll
    for (int i = 0; i < 8; ++i) {
        float4 o = make_float4(acc[i][0], acc[i][1], acc[i][2], acc[i][3]);
        *(float4*)&C[(size_t)(m0 + ty * 8 + i) * Nn + n0 + tx * 4] = o;
    }
}

// ---------------------------------------------------------------------------
// dt = softplus_thresh(dt_mm + dt_bias); dA = exp(dt * (-exp(A_log)))
// ---------------------------------------------------------------------------
__global__ void dt_kernel(float* __restrict__ dtio, float* __restrict__ dAo,
                          const float* __restrict__ dt_bias,
                          const float* __restrict__ A_log, int n)
{
    int i = blockIdx.x * 256 + threadIdx.x;
    if (i >= n) return;
    int h = i & (HEADS - 1);
    float x   = dtio[i] + dt_bias[h];
    float dtv = (x < 10.f) ? log1pf(expf(x)) : x;
    dtio[i] = dtv;
    dAo[i]  = expf(-dtv * expf(A_log[h]));
}

// ---------------------------------------------------------------------------
// Causal depthwise conv1d (K=4) + bias + silu.
// ---------------------------------------------------------------------------
__global__ void conv_kernel(const float* __restrict__ xin,
                            const float* __restrict__ cw,
                            const float* __restrict__ cb,
                            float* __restrict__ xout)
{
    int c  = blockIdx.x * 256 + threadIdx.x;
    int bt = blockIdx.y;
    int t  = bt & (LSEQ - 1);
    size_t i = (size_t)bt * CONV_DIM + c;
    float4 w = *(const float4*)(cw + (size_t)c * 4);
    float acc = cb[c];
    acc = fmaf(xin[i], w.w, acc);
    if (t >= 1) acc = fmaf(xin[i - CONV_DIM],     w.z, acc);
    if (t >= 2) acc = fmaf(xin[i - 2 * CONV_DIM], w.y, acc);
    if (t >= 3) acc = fmaf(xin[i - 3 * CONV_DIM], w.x, acc);
    xout[i] = acc / (1.f + expf(-acc));
}

// ---------------------------------------------------------------------------
// SSM scan, time-chunked LDS staging.
// Block = (b, h, p-half): 256 blocks x 256 threads (4 waves).
// Thread: nq = tid&7 (16 n-states), pl = tid>>3 (p row within half).
// Per chunk (T=32): prefetch next chunk B/C/x/dt/dA to regs (global latency
// hidden under current chunk's compute), stage to LDS, inner loop reads LDS
// only. B/C LDS layout skewed so the 8 nq b128-reads hit <=2-way banks.
// ---------------------------------------------------------------------------
__global__ __launch_bounds__(256) void scan_kernel(
    const float* __restrict__ xc,   // [B,L,CONV_DIM] post-conv
    const float* __restrict__ dt,   // [B,L,H]
    const float* __restrict__ dA,   // [B,L,H]
    const float* __restrict__ Dvec, // [H]
    float* __restrict__ y)          // [B,L,INTER]
{
    const int bid = blockIdx.x;
    const int b   = bid >> 7;
    const int h   = (bid >> 1) & 63;
    const int ph  = bid & 1;
    const int p0  = ph * 32;
    const int tid = threadIdx.x;
    const int nq  = tid & 7;        // n-chunk of 16
    const int pl  = tid >> 3;       // 0..31

    __shared__ float BCs[TCH][256]; // [t][skewed B(128) | skewed C(128)]
    __shared__ float xs[TCH][32];
    __shared__ float dts[TCH];
    __shared__ float dAs[TCH];

    const float* bcg = xc + (size_t)b * LSEQ * CONV_DIM + INTER;
    const float* xg  = xc + (size_t)b * LSEQ * CONV_DIM + h * 64 + p0;
    const float* dtg = dt + (size_t)b * LSEQ * HEADS + h;
    const float* dAg = dA + (size_t)b * LSEQ * HEADS + h;
    float*       yg  = y  + (size_t)b * LSEQ * INTER + h * 64 + p0;

    // loader roles
    const int lrow = tid >> 6;          // BC t-row base (0..3), +4*i
    const int lcol = (tid & 63) * 4;    // BC float col 0..252
    const int xrow = tid >> 3;          // x t-row 0..31
    const int xcol = (tid & 7) * 4;     // x float col 0..28
    // skewed LDS write position for this thread's BC word
    const int wword = tid & 63;         // float4 word 0..63 (B:0..31, C:32..63)
    const int chalf = wword & 31;
    const int wnq   = chalf >> 2;
    const int wskew = ((chalf & 3) + wnq) & 3;
    const int wpos  = ((wword < 32) ? 0 : 128) + wnq * 16 + wskew * 4;

    float4 bcr[8];
    float4 xr;
    float  dtr = 0.f, dAr = 0.f;

    auto load_chunk = [&](int t0) {
        #pragma unroll
        for (int i = 0; i < 8; ++i)
            bcr[i] = *(const float4*)(bcg + (size_t)(t0 + lrow + i * 4) * CONV_DIM + lcol);
        xr = *(const float4*)(xg + (size_t)(t0 + xrow) * CONV_DIM + xcol);
        if (tid < TCH)            dtr = dtg[(size_t)(t0 + tid) * HEADS];
        else if (tid < 2 * TCH)   dAr = dAg[(size_t)(t0 + tid - TCH) * HEADS];
    };
    auto store_chunk = [&]() {
        #pragma unroll
        for (int i = 0; i < 8; ++i)
            *(float4*)&BCs[lrow + i * 4][wpos] = bcr[i];
        *(float4*)&xs[xrow][xcol] = xr;
        if (tid < TCH)            dts[tid] = dtr;
        else if (tid < 2 * TCH)   dAs[tid - TCH] = dAr;
    };

    float st[16];
    #pragma unroll
    for (int j = 0; j < 16; ++j) st[j] = 0.f;
    const float Dh = Dvec[h];

    load_chunk(0);
    store_chunk();
    __syncthreads();
    load_chunk(TCH);

    const int NC = LSEQ / TCH;  // 64
    for (int c = 0; c < NC; ++c) {
        const int tbase = c * TCH;
        for (int t = 0; t < TCH; ++t) {
            float dtv = dts[t];
            float dav = dAs[t];
            float xv  = xs[t][pl];
            float dtx = dtv * xv;
            float acc = 0.f;
            #pragma unroll
            for (int k = 0; k < 4; ++k) {
                int s = (k + nq) & 3;
                float4 bv = *(const float4*)&BCs[t][nq * 16 + s * 4];
                float4 cv = *(const float4*)&BCs[t][128 + nq * 16 + s * 4];
                st[k*4+0] = fmaf(dav, st[k*4+0], dtx * bv.x);
                st[k*4+1] = fmaf(dav, st[k*4+1], dtx * bv.y);
                st[k*4+2] = fmaf(dav, st[k*4+2], dtx * bv.z);
                st[k*4+3] = fmaf(dav, st[k*4+3], dtx * bv.w);
                acc = fmaf(st[k*4+0], cv.x, acc);
                acc = fmaf(st[k*4+1], cv.y, acc);
                acc = fmaf(st[k*4+2], cv.z, acc);
                acc = fmaf(st[k*4+3], cv.w, acc);
            }
            acc += __shfl_xor(acc, 1);
            acc += __shfl_xor(acc, 2);
            acc += __shfl_xor(acc, 4);
            if (nq == 0)
                yg[(size_t)(tbase + t) * INTER + pl] = acc + Dh * xv;
        }
        __syncthreads();
        if (c + 1 < NC) {
            store_chunk();
            __syncthreads();
            if (c + 2 < NC) load_chunk((c + 2) * TCH);
        }
    }
}

// ---------------------------------------------------------------------------
// Gated RMSNorm (G=1: full 4096 row). normed written in-place over gate.
// ---------------------------------------------------------------------------
__global__ __launch_bounds__(256) void norm_kernel(
    const float* __restrict__ y, float* __restrict__ gate,
    const float* __restrict__ w)
{
    const int row = blockIdx.x;
    const float* yr = y    + (size_t)row * INTER;
    float*       gr = gate + (size_t)row * INTER;
    const int tid = threadIdx.x;

    float v[16];
    float ss = 0.f;
    #pragma unroll
    for (int i = 0; i < 16; ++i) {
        int idx = tid + i * 256;
        float hv = yr[idx];
        float g  = gr[idx];
        float sg = g / (1.f + expf(-g));
        float val = hv * sg;
        v[i] = val;
        ss = fmaf(val, val, ss);
    }
    #pragma unroll
    for (int o = 32; o > 0; o >>= 1) ss += __shfl_xor(ss, o);
    __shared__ float part[4];
    if ((tid & 63) == 0) part[tid >> 6] = ss;
    __syncthreads();
    float tot  = part[0] + part[1] + part[2] + part[3];
    float rinv = rsqrtf(tot * (1.f / INTER) + EPS);
    #pragma unroll
    for (int i = 0; i < 16; ++i) {
        int idx = tid + i * 256;
        gr[idx] = w[idx] * v[i] * rinv;
    }
}

// ---------------------------------------------------------------------------
extern "C" void kernel_launch(void* const* d_in, const int* in_sizes, int n_in,
                              void* d_out, int out_size, void* d_ws, size_t ws_size,
                              hipStream_t stream)
{
    const float* hs      = (const float*)d_in[0];
    const float* W_z     = (const float*)d_in[1];
    const float* W_xBC   = (const float*)d_in[2];
    const float* W_dt    = (const float*)d_in[3];
    const float* conv_w  = (const float*)d_in[4];
    const float* conv_b  = (const float*)d_in[5];
    const float* dt_bias = (const float*)d_in[6];
    const float* A_log   = (const float*)d_in[7];
    const float* Dv      = (const float*)d_in[8];
    const float* norm_w  = (const float*)d_in[9];
    const float* W_out   = (const float*)d_in[10];
    float* out = (float*)d_out;
    float* ws  = (float*)d_ws;

    float* gate  = ws;                 // 4096*4096
    float* xpre  = ws + 16777216;      // 4096*4352 (reused as y)
    float* xconv = ws + 34603008;      // 4096*4352
    float* dtb   = ws + 52428800;      // 4096*64
    float* dAb   = ws + 52690944;      // 4096*64
    float* yb    = xpre;

    const int M = B_SZ * LSEQ;         // 4096

    gemm_f32<<<dim3(INTER / 64,    M / 128), 256, 0, stream>>>(hs, W_z,   gate, M, INTER,    DMODEL);
    gemm_f32<<<dim3(CONV_DIM / 64, M / 128), 256, 0, stream>>>(hs, W_xBC, xpre, M, CONV_DIM, DMODEL);
    gemm_f32<<<dim3(HEADS / 64,    M / 128), 256, 0, stream>>>(hs, W_dt,  dtb,  M, HEADS,    DMODEL);

    dt_kernel<<<(M * HEADS + 255) / 256, 256, 0, stream>>>(dtb, dAb, dt_bias, A_log, M * HEADS);

    conv_kernel<<<dim3(CONV_DIM / 256, M), 256, 0, stream>>>(xpre, conv_w, conv_b, xconv);

    scan_kernel<<<B_SZ * HEADS * 2, 256, 0, stream>>>(xconv, dtb, dAb, Dv, yb);

    norm_kernel<<<M, 256, 0, stream>>>(yb, gate, norm_w);

    gemm_f32<<<dim3(DMODEL / 64, M / 128), 256, 0, stream>>>(gate, W_out, out, M, DMODEL, INTER);
}

// Round 3
// 1223.892 us; speedup vs baseline: 5.3892x; 3.0388x over previous
//
#include <hip/hip_runtime.h>
#include <hip/hip_bf16.h>
#include <math.h>

typedef unsigned short u16;
typedef unsigned int   u32;
typedef __attribute__((ext_vector_type(8))) short short8;
typedef __attribute__((ext_vector_type(4))) float f32x4;

#define B_SZ     2
#define LSEQ     2048
#define DMODEL   2048
#define INTER    4096
#define HEADS    64
#define CONV_DIM 4352            /* INTER + 2*128 */
#define XCOLS    4480            /* CONV_DIM + 64 dt cols + 64 zero-pad */
#define EPS      1e-5f
#define TCH      32

__device__ __forceinline__ float bf2f(u16 u) {
    u32 v = ((u32)u) << 16;
    return __builtin_bit_cast(float, v);
}
__device__ __forceinline__ u16 f2bf(float x) {
    __hip_bfloat16 h = __float2bfloat16(x);   // RNE
    return __builtin_bit_cast(u16, h);
}
__device__ __forceinline__ void gl2lds16(const void* g, void* l) {
    __builtin_amdgcn_global_load_lds(
        (const __attribute__((address_space(1))) u32*)g,
        (__attribute__((address_space(3))) u32*)l, 16, 0, 0);
}

// ---------------------------------------------------------------------------
// fp32 -> bf16 elementwise (n4 = count/4)
// ---------------------------------------------------------------------------
__global__ __launch_bounds__(256) void cvt_f32_bf16(
    const float* __restrict__ in, u16* __restrict__ out, int n4)
{
    int i = blockIdx.x * 256 + threadIdx.x;
    if (i >= n4) return;
    float4 v = ((const float4*)in)[i];
    ushort4 o;
    o.x = f2bf(v.x); o.y = f2bf(v.y); o.z = f2bf(v.z); o.w = f2bf(v.w);
    ((ushort4*)out)[i] = o;
}

// ---------------------------------------------------------------------------
// Transpose + convert: in fp32 [R][C] -> out bf16 [C][R]. R,C multiples of 64.
// ---------------------------------------------------------------------------
__global__ __launch_bounds__(256) void tr_f32_bf16(
    const float* __restrict__ in, u16* __restrict__ out, int R, int C)
{
    __shared__ u16 tile[64][68];
    const int r0 = blockIdx.y * 64, c0 = blockIdx.x * 64;
    const int tr = threadIdx.x >> 4, tc = (threadIdx.x & 15) * 4;
    #pragma unroll
    for (int i = 0; i < 4; ++i) {
        int r = tr + i * 16;
        float4 v = *(const float4*)(in + (size_t)(r0 + r) * C + c0 + tc);
        tile[r][tc + 0] = f2bf(v.x);
        tile[r][tc + 1] = f2bf(v.y);
        tile[r][tc + 2] = f2bf(v.z);
        tile[r][tc + 3] = f2bf(v.w);
    }
    __syncthreads();
    #pragma unroll
    for (int i = 0; i < 4; ++i) {
        int oc = tr + i * 16;
        ushort4 o;
        o.x = tile[tc + 0][oc];
        o.y = tile[tc + 1][oc];
        o.z = tile[tc + 2][oc];
        o.w = tile[tc + 3][oc];
        *(ushort4*)(out + (size_t)(c0 + oc) * R + r0 + tc) = o;
    }
}

// ---------------------------------------------------------------------------
// bf16 MFMA GEMM, NT form (m97 structure): C[M,N] = A[M,K] @ Bt[N,K]^T.
// 128x128 tile, BK=32, 4 waves (each 64x64 = 4x4 MFMA 16x16x32 tiles).
// global_load_lds width=16 staging, LDS row-major [128][32] bf16 (no pad).
// M,N % 128 == 0, K % 32 == 0.
// ---------------------------------------------------------------------------
template<int OUT_BF16>
__global__ __launch_bounds__(256) void gemm_nt(
    const u16* __restrict__ A, const u16* __restrict__ Bt,
    void* __restrict__ Co, int M, int N, int K)
{
    __shared__ __align__(16) u16 As[128 * 32];
    __shared__ __align__(16) u16 Bs[128 * 32];
    const int tid  = threadIdx.x;
    const int wave = tid >> 6, lane = tid & 63;
    const int m0 = blockIdx.y * 128, n0 = blockIdx.x * 128;
    const int wm = (wave >> 1) * 64, wn = (wave & 1) * 64;

    // staging: wave w stages rows [16w,16w+16) (+64); lane l -> row 16w+(l>>2), col (l&3)*8
    const int srow = wave * 16 + (lane >> 2);
    const int scol = (lane & 3) * 8;
    const u16* ag = A  + (size_t)(m0 + srow) * K + scol;
    const u16* bg = Bt + (size_t)(n0 + srow) * K + scol;
    u16* asl = As + wave * (16 * 32);   // wave-uniform LDS base; HW adds lane*16B
    u16* bsl = Bs + wave * (16 * 32);

    f32x4 acc[4][4];
    #pragma unroll
    for (int i = 0; i < 4; ++i)
        #pragma unroll
        for (int j = 0; j < 4; ++j) acc[i][j] = (f32x4)0.f;

    const int lr = lane & 15, lq = lane >> 4;
    const u16* arp = As + (wm + lr) * 32 + lq * 8;
    const u16* brp = Bs + (wn + lr) * 32 + lq * 8;

    for (int k0 = 0; k0 < K; k0 += 32) {
        __syncthreads();                       // prior-iter LDS reads done
        gl2lds16(ag + k0,          asl);
        gl2lds16(ag + 64 * K + k0, asl + 64 * 32);
        gl2lds16(bg + k0,          bsl);
        gl2lds16(bg + 64 * K + k0, bsl + 64 * 32);
        __syncthreads();                       // vmcnt(0) drained before barrier

        short8 af[4], bfr[4];
        #pragma unroll
        for (int i = 0; i < 4; ++i) af[i]  = *(const short8*)(arp + i * 16 * 32);
        #pragma unroll
        for (int j = 0; j < 4; ++j) bfr[j] = *(const short8*)(brp + j * 16 * 32);
        #pragma unroll
        for (int i = 0; i < 4; ++i)
            #pragma unroll
            for (int j = 0; j < 4; ++j)
                acc[i][j] = __builtin_amdgcn_mfma_f32_16x16x32_bf16(
                    af[i], bfr[j], acc[i][j], 0, 0, 0);
    }

    // C/D layout: col = lane&15, row = (lane>>4)*4 + reg  [m89-verified]
    #pragma unroll
    for (int i = 0; i < 4; ++i)
        #pragma unroll
        for (int j = 0; j < 4; ++j)
            #pragma unroll
            for (int r = 0; r < 4; ++r) {
                int row = m0 + wm + i * 16 + lq * 4 + r;
                int col = n0 + wn + j * 16 + lr;
                if (OUT_BF16)
                    ((u16*)Co)[(size_t)row * N + col] = f2bf(acc[i][j][r]);
                else
                    ((float*)Co)[(size_t)row * N + col] = acc[i][j][r];
            }
}

// ---------------------------------------------------------------------------
// dt = softplus(dt_mm + bias); dA = exp(-dt*exp(A_log)). dt_mm read from
// xpre bf16 cols [4352, 4416).
// ---------------------------------------------------------------------------
__global__ void dt_kernel(const u16* __restrict__ xpre,
                          float* __restrict__ dtb, float* __restrict__ dAb,
                          const float* __restrict__ dt_bias,
                          const float* __restrict__ A_log, int n)
{
    int i = blockIdx.x * 256 + threadIdx.x;
    if (i >= n) return;
    int h = i & 63, row = i >> 6;
    float x = bf2f(xpre[(size_t)row * XCOLS + CONV_DIM + h]) + dt_bias[h];
    float dtv = (x < 10.f) ? log1pf(expf(x)) : x;
    dtb[i] = dtv;
    dAb[i] = expf(-dtv * expf(A_log[h]));
}

// ---------------------------------------------------------------------------
// Causal depthwise conv1d (K=4) + bias + silu, bf16 in [4096][XCOLS] ->
// bf16 out [4096][CONV_DIM].
// ---------------------------------------------------------------------------
__global__ void conv_kernel(const u16* __restrict__ xin,
                            const float* __restrict__ cw,
                            const float* __restrict__ cb,
                            u16* __restrict__ xout)
{
    int c  = blockIdx.x * 256 + threadIdx.x;   // 0..4351
    int bt = blockIdx.y;
    int t  = bt & (LSEQ - 1);
    const u16* xi = xin + (size_t)bt * XCOLS + c;
    float4 w = *(const float4*)(cw + (size_t)c * 4);
    float acc = cb[c];
    acc = fmaf(bf2f(xi[0]), w.w, acc);
    if (t >= 1) acc = fmaf(bf2f(*(xi - XCOLS)),     w.z, acc);
    if (t >= 2) acc = fmaf(bf2f(*(xi - 2 * XCOLS)), w.y, acc);
    if (t >= 3) acc = fmaf(bf2f(*(xi - 3 * XCOLS)), w.x, acc);
    xout[(size_t)bt * CONV_DIM + c] = f2bf(acc / (1.f + expf(-acc)));
}

// ---------------------------------------------------------------------------
// SSM scan. 512 blocks x 256 thr; block = (b, h, p-quarter of 16 rows).
// Lane: pl = tid>>4 (p row), nq = tid&15 (8 n-states, one 16B b128 read).
// B/C staged bf16 in LDS: row t = 512 B; lane reads at byte nq*16 -> 2-way
// bank aliasing only (free). 2 blocks/CU (2 waves/SIMD) for latency hiding.
// ---------------------------------------------------------------------------
__global__ __launch_bounds__(256) void scan_kernel(
    const u16* __restrict__ xc,    // [B,L,CONV_DIM] bf16 post-conv
    const float* __restrict__ dtg_, const float* __restrict__ dAg_,
    const float* __restrict__ Dvec,
    u16* __restrict__ y)           // [B,L,INTER] bf16
{
    const int bid = blockIdx.x;
    const int b  = bid >> 8;
    const int h  = (bid >> 2) & 63;
    const int pq = bid & 3;
    const int p0 = pq * 16;
    const int tid = threadIdx.x;
    const int pl = tid >> 4;
    const int nq = tid & 15;

    __shared__ __align__(16) u16 BCs[TCH][256];   // [t][B(128)|C(128)] bf16
    __shared__ __align__(16) u16 xs[TCH][16];
    __shared__ float dts[TCH], dAs[TCH];

    const u16* bcg = xc + (size_t)b * LSEQ * CONV_DIM + INTER;
    const u16* xg  = xc + (size_t)b * LSEQ * CONV_DIM + h * 64 + p0;
    const float* dtg = dtg_ + (size_t)b * LSEQ * HEADS + h;
    const float* dAg = dAg_ + (size_t)b * LSEQ * HEADS + h;
    u16* yg = y + (size_t)b * LSEQ * INTER + h * 64 + p0;

    uint4 bcr[4]; uint4 xr = {0,0,0,0}; float dtr = 0.f, dAr = 0.f;

    auto load_chunk = [&](int t0) {
        #pragma unroll
        for (int k = 0; k < 4; ++k) {
            int s = tid + 256 * k;
            int t = s >> 5, off = (s & 31) * 8;
            bcr[k] = *(const uint4*)(bcg + (size_t)(t0 + t) * CONV_DIM + off);
        }
        if (tid < 64) {
            int t = tid >> 1, off = (tid & 1) * 8;
            xr = *(const uint4*)(xg + (size_t)(t0 + t) * CONV_DIM + off);
        } else if (tid < 96) {
            dtr = dtg[(size_t)(t0 + tid - 64) * HEADS];
        } else if (tid < 128) {
            dAr = dAg[(size_t)(t0 + tid - 96) * HEADS];
        }
    };
    auto store_chunk = [&]() {
        #pragma unroll
        for (int k = 0; k < 4; ++k) {
            int s = tid + 256 * k;
            int t = s >> 5, off = (s & 31) * 8;
            *(uint4*)&BCs[t][off] = bcr[k];
        }
        if (tid < 64) {
            int t = tid >> 1, off = (tid & 1) * 8;
            *(uint4*)&xs[t][off] = xr;
        } else if (tid < 96) {
            dts[tid - 64] = dtr;
        } else if (tid < 128) {
            dAs[tid - 96] = dAr;
        }
    };

    float st[8];
    #pragma unroll
    for (int j = 0; j < 8; ++j) st[j] = 0.f;
    const float Dh = Dvec[h];

    load_chunk(0);
    store_chunk();
    __syncthreads();
    load_chunk(TCH);

    const int NC = LSEQ / TCH;
    for (int c = 0; c < NC; ++c) {
        #pragma unroll 4
        for (int t = 0; t < TCH; ++t) {
            float dtc = dts[t], dac = dAs[t];
            float xv  = bf2f(xs[t][pl]);
            uint4 br = *(const uint4*)&BCs[t][nq * 8];
            uint4 cr = *(const uint4*)&BCs[t][128 + nq * 8];
            float dtx = dtc * xv;
            float acc = 0.f;
            const u32* bw = (const u32*)&br;
            const u32* cw = (const u32*)&cr;
            #pragma unroll
            for (int e = 0; e < 4; ++e) {
                float b0 = bf2f((u16)(bw[e] & 0xffffu));
                float b1 = bf2f((u16)(bw[e] >> 16));
                float c0 = bf2f((u16)(cw[e] & 0xffffu));
                float c1 = bf2f((u16)(cw[e] >> 16));
                st[2*e]   = fmaf(dac, st[2*e],   dtx * b0);
                st[2*e+1] = fmaf(dac, st[2*e+1], dtx * b1);
                acc = fmaf(st[2*e],   c0, acc);
                acc = fmaf(st[2*e+1], c1, acc);
            }
            acc += __shfl_xor(acc, 1);
            acc += __shfl_xor(acc, 2);
            acc += __shfl_xor(acc, 4);
            acc += __shfl_xor(acc, 8);
            if (nq == 0)
                yg[(size_t)(c * TCH + t) * INTER + pl] = f2bf(acc + Dh * xv);
        }
        __syncthreads();
        if (c + 1 < NC) {
            store_chunk();
            __syncthreads();
            if (c + 2 < NC) load_chunk((c + 2) * TCH);
        }
    }
}

// ---------------------------------------------------------------------------
// Gated RMSNorm (G=1). y bf16, gate bf16; normed bf16 written in-place.
// ---------------------------------------------------------------------------
__global__ __launch_bounds__(256) void norm_kernel(
    const u16* __restrict__ y, u16* __restrict__ gate,
    const float* __restrict__ w)
{
    const int row = blockIdx.x;
    const u16* yr = y    + (size_t)row * INTER;
    u16*       gr = gate + (size_t)row * INTER;
    const int tid = threadIdx.x;

    float v[16];
    float ss = 0.f;
    #pragma unroll
    for (int i = 0; i < 16; ++i) {
        int idx = tid + i * 256;
        float hv = bf2f(yr[idx]);
        float g  = bf2f(gr[idx]);
        float val = hv * (g / (1.f + expf(-g)));
        v[i] = val;
        ss = fmaf(val, val, ss);
    }
    #pragma unroll
    for (int o = 32; o > 0; o >>= 1) ss += __shfl_xor(ss, o);
    __shared__ float part[4];
    if ((tid & 63) == 0) part[tid >> 6] = ss;
    __syncthreads();
    float tot  = part[0] + part[1] + part[2] + part[3];
    float rinv = rsqrtf(tot * (1.f / INTER) + EPS);
    #pragma unroll
    for (int i = 0; i < 16; ++i) {
        int idx = tid + i * 256;
        gr[idx] = f2bf(w[idx] * v[i] * rinv);
    }
}

// ---------------------------------------------------------------------------
extern "C" void kernel_launch(void* const* d_in, const int* in_sizes, int n_in,
                              void* d_out, int out_size, void* d_ws, size_t ws_size,
                              hipStream_t stream)
{
    const float* hs      = (const float*)d_in[0];
    const float* W_z     = (const float*)d_in[1];
    const float* W_xBC   = (const float*)d_in[2];
    const float* W_dt    = (const float*)d_in[3];
    const float* conv_w  = (const float*)d_in[4];
    const float* conv_b  = (const float*)d_in[5];
    const float* dt_bias = (const float*)d_in[6];
    const float* A_log   = (const float*)d_in[7];
    const float* Dv      = (const float*)d_in[8];
    const float* norm_w  = (const float*)d_in[9];
    const float* W_out   = (const float*)d_in[10];
    float* out = (float*)d_out;
    char*  w8  = (char*)d_ws;

    // workspace layout (bytes)
    u16* hs_bf  = (u16*)(w8 + 0);            // 4096*2048*2  = 16777216
    u16* Wt_z   = (u16*)(w8 + 16777216);     // 4096*2048*2  = 16777216
    u16* Wt_xc  = (u16*)(w8 + 33554432);     // 4480*2048*2  = 18350080
    u16* Wt_out = (u16*)(w8 + 51904512);     // 2048*4096*2  = 16777216
    u16* gate   = (u16*)(w8 + 68681728);     // 4096*4096*2  = 33554432
    u16* xpre   = (u16*)(w8 + 102236160);    // 4096*4480*2  = 36700160
    u16* xconv  = (u16*)(w8 + 138936320);    // 4096*4352*2  = 35651584
    float* dtb  = (float*)(w8 + 174587904);  // 4096*64*4    = 1048576
    float* dAb  = (float*)(w8 + 175636480);  // 4096*64*4    = 1048576
    u16* yb = xpre;                          // alias: xpre dead after conv+dt

    const int M = B_SZ * LSEQ;               // 4096

    // bf16 conversions / weight transposes
    cvt_f32_bf16<<<(M * DMODEL / 4 + 255) / 256, 256, 0, stream>>>(hs, hs_bf, M * DMODEL / 4);
    tr_f32_bf16<<<dim3(INTER / 64,    DMODEL / 64), 256, 0, stream>>>(W_z,   Wt_z,  DMODEL, INTER);
    tr_f32_bf16<<<dim3(CONV_DIM / 64, DMODEL / 64), 256, 0, stream>>>(W_xBC, Wt_xc, DMODEL, CONV_DIM);
    tr_f32_bf16<<<dim3(1,             DMODEL / 64), 256, 0, stream>>>(W_dt,  Wt_xc + (size_t)CONV_DIM * DMODEL, DMODEL, 64);
    hipMemsetAsync(Wt_xc + (size_t)(CONV_DIM + 64) * DMODEL, 0, (size_t)64 * DMODEL * 2, stream);
    tr_f32_bf16<<<dim3(DMODEL / 64,   INTER / 64),  256, 0, stream>>>(W_out, Wt_out, INTER, DMODEL);

    // projections (dt fused into xBC GEMM as extra columns)
    gemm_nt<1><<<dim3(INTER / 128, M / 128), 256, 0, stream>>>(hs_bf, Wt_z,  (void*)gate, M, INTER, DMODEL);
    gemm_nt<1><<<dim3(XCOLS / 128, M / 128), 256, 0, stream>>>(hs_bf, Wt_xc, (void*)xpre, M, XCOLS, DMODEL);

    dt_kernel<<<(M * HEADS + 255) / 256, 256, 0, stream>>>(xpre, dtb, dAb, dt_bias, A_log, M * HEADS);
    conv_kernel<<<dim3(CONV_DIM / 256, M), 256, 0, stream>>>(xpre, conv_w, conv_b, xconv);

    scan_kernel<<<B_SZ * HEADS * 4, 256, 0, stream>>>(xconv, dtb, dAb, Dv, yb);

    norm_kernel<<<M, 256, 0, stream>>>(yb, gate, norm_w);

    gemm_nt<0><<<dim3(DMODEL / 128, M / 128), 256, 0, stream>>>(gate, Wt_out, (void*)out, M, DMODEL, INTER);
}

// Round 4
// 699.892 us; speedup vs baseline: 9.4240x; 1.7487x over previous
//
#include <hip/hip_runtime.h>
#include <hip/hip_bf16.h>
#include <math.h>

typedef unsigned short u16;
typedef unsigned int   u32;
typedef __attribute__((ext_vector_type(8))) short short8;
typedef __attribute__((ext_vector_type(4))) float f32x4;

#define B_SZ     2
#define LSEQ     2048
#define DMODEL   2048
#define INTER    4096
#define HEADS    64
#define NSTATE   128
#define CONV_DIM 4352            /* INTER + 2*128 */
#define XCOLS    4480            /* CONV_DIM + 64 dt cols + 64 zero-pad */
#define EPS      1e-5f
#define QCH      64              /* SSD chunk length */
#define NCHUNK   (LSEQ / QCH)    /* 32 */

__device__ __forceinline__ float bf2f(u16 u) {
    u32 v = ((u32)u) << 16;
    return __builtin_bit_cast(float, v);
}
__device__ __forceinline__ u16 f2bf(float x) {
    __hip_bfloat16 h = __float2bfloat16(x);   // RNE
    return __builtin_bit_cast(u16, h);
}
__device__ __forceinline__ u32 pack2(float lo, float hi) {
    return (u32)f2bf(lo) | ((u32)f2bf(hi) << 16);
}
__device__ __forceinline__ void gl2lds16(const void* g, void* l) {
    __builtin_amdgcn_global_load_lds(
        (const __attribute__((address_space(1))) u32*)g,
        (__attribute__((address_space(3))) u32*)l, 16, 0, 0);
}

// ---------------------------------------------------------------------------
// fp32 -> bf16 elementwise (n4 = count/4)
// ---------------------------------------------------------------------------
__global__ __launch_bounds__(256) void cvt_f32_bf16(
    const float* __restrict__ in, u16* __restrict__ out, int n4)
{
    int i = blockIdx.x * 256 + threadIdx.x;
    if (i >= n4) return;
    float4 v = ((const float4*)in)[i];
    ushort4 o;
    o.x = f2bf(v.x); o.y = f2bf(v.y); o.z = f2bf(v.z); o.w = f2bf(v.w);
    ((ushort4*)out)[i] = o;
}

// ---------------------------------------------------------------------------
// Transpose + convert: in fp32 [R][C] -> out bf16 [C][R]. R,C multiples of 64.
// ---------------------------------------------------------------------------
__global__ __launch_bounds__(256) void tr_f32_bf16(
    const float* __restrict__ in, u16* __restrict__ out, int R, int C)
{
    __shared__ u16 tile[64][68];
    const int r0 = blockIdx.y * 64, c0 = blockIdx.x * 64;
    const int tr = threadIdx.x >> 4, tc = (threadIdx.x & 15) * 4;
    #pragma unroll
    for (int i = 0; i < 4; ++i) {
        int r = tr + i * 16;
        float4 v = *(const float4*)(in + (size_t)(r0 + r) * C + c0 + tc);
        tile[r][tc + 0] = f2bf(v.x);
        tile[r][tc + 1] = f2bf(v.y);
        tile[r][tc + 2] = f2bf(v.z);
        tile[r][tc + 3] = f2bf(v.w);
    }
    __syncthreads();
    #pragma unroll
    for (int i = 0; i < 4; ++i) {
        int oc = tr + i * 16;
        ushort4 o;
        o.x = tile[tc + 0][oc];
        o.y = tile[tc + 1][oc];
        o.z = tile[tc + 2][oc];
        o.w = tile[tc + 3][oc];
        *(ushort4*)(out + (size_t)(c0 + oc) * R + r0 + tc) = o;
    }
}

// ---------------------------------------------------------------------------
// bf16 MFMA GEMM, NT form (m97 structure): C[M,N] = A[M,K] @ Bt[N,K]^T.
// ---------------------------------------------------------------------------
template<int OUT_BF16>
__global__ __launch_bounds__(256) void gemm_nt(
    const u16* __restrict__ A, const u16* __restrict__ Bt,
    void* __restrict__ Co, int M, int N, int K)
{
    __shared__ __align__(16) u16 As[128 * 32];
    __shared__ __align__(16) u16 Bs[128 * 32];
    const int tid  = threadIdx.x;
    const int wave = tid >> 6, lane = tid & 63;
    const int m0 = blockIdx.y * 128, n0 = blockIdx.x * 128;
    const int wm = (wave >> 1) * 64, wn = (wave & 1) * 64;

    const int srow = wave * 16 + (lane >> 2);
    const int scol = (lane & 3) * 8;
    const u16* ag = A  + (size_t)(m0 + srow) * K + scol;
    const u16* bg = Bt + (size_t)(n0 + srow) * K + scol;
    u16* asl = As + wave * (16 * 32);
    u16* bsl = Bs + wave * (16 * 32);

    f32x4 acc[4][4];
    #pragma unroll
    for (int i = 0; i < 4; ++i)
        #pragma unroll
        for (int j = 0; j < 4; ++j) acc[i][j] = (f32x4)0.f;

    const int lr = lane & 15, lq = lane >> 4;
    const u16* arp = As + (wm + lr) * 32 + lq * 8;
    const u16* brp = Bs + (wn + lr) * 32 + lq * 8;

    for (int k0 = 0; k0 < K; k0 += 32) {
        __syncthreads();
        gl2lds16(ag + k0,          asl);
        gl2lds16(ag + 64 * K + k0, asl + 64 * 32);
        gl2lds16(bg + k0,          bsl);
        gl2lds16(bg + 64 * K + k0, bsl + 64 * 32);
        __syncthreads();

        short8 af[4], bfr[4];
        #pragma unroll
        for (int i = 0; i < 4; ++i) af[i]  = *(const short8*)(arp + i * 16 * 32);
        #pragma unroll
        for (int j = 0; j < 4; ++j) bfr[j] = *(const short8*)(brp + j * 16 * 32);
        #pragma unroll
        for (int i = 0; i < 4; ++i)
            #pragma unroll
            for (int j = 0; j < 4; ++j)
                acc[i][j] = __builtin_amdgcn_mfma_f32_16x16x32_bf16(
                    af[i], bfr[j], acc[i][j], 0, 0, 0);
    }

    #pragma unroll
    for (int i = 0; i < 4; ++i)
        #pragma unroll
        for (int j = 0; j < 4; ++j)
            #pragma unroll
            for (int r = 0; r < 4; ++r) {
                int row = m0 + wm + i * 16 + lq * 4 + r;
                int col = n0 + wn + j * 16 + lr;
                if (OUT_BF16)
                    ((u16*)Co)[(size_t)row * N + col] = f2bf(acc[i][j][r]);
                else
                    ((float*)Co)[(size_t)row * N + col] = acc[i][j][r];
            }
}

// ---------------------------------------------------------------------------
// dt = softplus(dt_mm + bias). dt_mm read from xpre bf16 cols [4352,4416).
// ---------------------------------------------------------------------------
__global__ void dt_kernel(const u16* __restrict__ xpre,
                          float* __restrict__ dtb,
                          const float* __restrict__ dt_bias, int n)
{
    int i = blockIdx.x * 256 + threadIdx.x;
    if (i >= n) return;
    int h = i & 63, row = i >> 6;
    float x = bf2f(xpre[(size_t)row * XCOLS + CONV_DIM + h]) + dt_bias[h];
    dtb[i] = (x < 10.f) ? log1pf(expf(x)) : x;
}

// ---------------------------------------------------------------------------
// Causal depthwise conv1d (K=4) + bias + silu.
// ---------------------------------------------------------------------------
__global__ void conv_kernel(const u16* __restrict__ xin,
                            const float* __restrict__ cw,
                            const float* __restrict__ cb,
                            u16* __restrict__ xout)
{
    int c  = blockIdx.x * 256 + threadIdx.x;
    int bt = blockIdx.y;
    int t  = bt & (LSEQ - 1);
    const u16* xi = xin + (size_t)bt * XCOLS + c;
    float4 w = *(const float4*)(cw + (size_t)c * 4);
    float acc = cb[c];
    acc = fmaf(bf2f(xi[0]), w.w, acc);
    if (t >= 1) acc = fmaf(bf2f(*(xi - XCOLS)),     w.z, acc);
    if (t >= 2) acc = fmaf(bf2f(*(xi - 2 * XCOLS)), w.y, acc);
    if (t >= 3) acc = fmaf(bf2f(*(xi - 3 * XCOLS)), w.x, acc);
    xout[(size_t)bt * CONV_DIM + c] = f2bf(acc / (1.f + expf(-acc)));
}

// ---------------------------------------------------------------------------
// SSD pass 1: per-(b,h,chunk) outgoing state T[p][n] = sum_j Xw[j][p] B[j][n],
// Xw[j][p] = dt_j * e^{cumQ - cum_j} * x[j][p].  Grid 4096, 256 thr.
// Also writes decayQ[bh*32+c] = e^{cumQ}.
// ---------------------------------------------------------------------------
__global__ __launch_bounds__(256) void ssd_chunk_state(
    const u16* __restrict__ xc, const float* __restrict__ dtb,
    const float* __restrict__ A_log,
    u16* __restrict__ Tg, float* __restrict__ decayQ)
{
    const int bid = blockIdx.x;
    const int b = bid >> 11, h = (bid >> 5) & 63, c = bid & 31;
    const int t0 = c * QCH;
    const int tid = threadIdx.x;
    const int wave = tid >> 6, lane = tid & 63;
    const int lr = lane & 15, lq = lane >> 4;

    __shared__ __align__(16) u16 BT[128][72];   // B^T: [n][j]
    __shared__ __align__(16) u16 XwT[64][72];   // Xw^T: [p][j]
    __shared__ float sclL[QCH];

    const u16* xg = xc + (size_t)b * LSEQ * CONV_DIM;

    if (tid < 64) {
        float dtv = dtb[((size_t)b * LSEQ + t0 + tid) * HEADS + h];
        float a = -dtv * expf(A_log[h]);
        float s = a;
        #pragma unroll
        for (int off = 1; off < 64; off <<= 1) {
            float o = __shfl_up(s, off, 64);
            if (tid >= off) s += o;
        }
        float cq = __shfl(s, 63, 64);
        sclL[tid] = dtv * expf(cq - s);           // dt_j * e^{cumQ - cum_j}
        if (tid == 0) decayQ[((b * 64 + h) << 5) + c] = expf(cq);
    }
    __syncthreads();

    #pragma unroll
    for (int r = 0; r < 16; ++r) {
        int idx = tid + 256 * r, j = idx >> 6, p = idx & 63;
        float v = bf2f(xg[(size_t)(t0 + j) * CONV_DIM + h * 64 + p]);
        XwT[p][j] = f2bf(v * sclL[j]);
    }
    #pragma unroll
    for (int r = 0; r < 32; ++r) {
        int idx = tid + 256 * r, j = idx >> 7, n = idx & 127;
        BT[n][j] = xg[(size_t)(t0 + j) * CONV_DIM + INTER + n];
    }
    __syncthreads();

    f32x4 acc[8];
    #pragma unroll
    for (int i = 0; i < 8; ++i) acc[i] = (f32x4)0.f;
    #pragma unroll
    for (int k0 = 0; k0 < QCH; k0 += 32) {
        short8 af = *(const short8*)&XwT[wave * 16 + lr][k0 + lq * 8];
        #pragma unroll
        for (int nt = 0; nt < 8; ++nt) {
            short8 bfr = *(const short8*)&BT[nt * 16 + lr][k0 + lq * 8];
            acc[nt] = __builtin_amdgcn_mfma_f32_16x16x32_bf16(af, bfr, acc[nt], 0, 0, 0);
        }
    }
    u16* To = Tg + ((((size_t)(b * 64 + h)) * NCHUNK + c) * 64) * 128;
    #pragma unroll
    for (int nt = 0; nt < 8; ++nt)
        #pragma unroll
        for (int r = 0; r < 4; ++r)
            To[(wave * 16 + lq * 4 + r) * 128 + nt * 16 + lr] = f2bf(acc[nt][r]);
}

// ---------------------------------------------------------------------------
// SSD pass 2: sequential recurrence over chunks. Grid 128 (b*h), 256 thr.
// In-place: reads T_c, overwrites it with S_prev_c (state BEFORE chunk c),
// then S = decayQ_c * S + T_c.  Thread owns p=tid>>2, n in [(tid&3)*32, +32).
// ---------------------------------------------------------------------------
__global__ __launch_bounds__(256) void ssd_state_scan(
    u16* __restrict__ Tg, const float* __restrict__ decayQ)
{
    const int bh = blockIdx.x, tid = threadIdx.x;
    const int p = tid >> 2, nb = (tid & 3) * 32;
    float S[32];
    #pragma unroll
    for (int m = 0; m < 32; ++m) S[m] = 0.f;

    for (int c = 0; c < NCHUNK; ++c) {
        u16* base = Tg + ((((size_t)bh * NCHUNK + c) * 64 + p) * 128) + nb;
        uint4 tv[4];
        #pragma unroll
        for (int k = 0; k < 4; ++k) tv[k] = *(const uint4*)(base + k * 8);
        #pragma unroll
        for (int k = 0; k < 4; ++k) {
            uint4 sv;
            sv.x = pack2(S[k*8+0], S[k*8+1]);
            sv.y = pack2(S[k*8+2], S[k*8+3]);
            sv.z = pack2(S[k*8+4], S[k*8+5]);
            sv.w = pack2(S[k*8+6], S[k*8+7]);
            *(uint4*)(base + k * 8) = sv;
        }
        float dq = decayQ[(bh << 5) + c];
        #pragma unroll
        for (int k = 0; k < 4; ++k) {
            const u32* w = (const u32*)&tv[k];
            #pragma unroll
            for (int e = 0; e < 4; ++e) {
                S[k*8 + e*2]     = fmaf(dq, S[k*8 + e*2],     bf2f((u16)(w[e] & 0xffffu)));
                S[k*8 + e*2 + 1] = fmaf(dq, S[k*8 + e*2 + 1], bf2f((u16)(w[e] >> 16)));
            }
        }
    }
}

// ---------------------------------------------------------------------------
// SSD pass 3: per-(b,h,chunk) output.
//   G = C·B^T  [64,64] (K=128); P = G ∘ M, M[i][j]=e^{cum_i-cum_j}dt_j (j<=i)
//   Y = P·X (K=64) + diag(e^{cum_i})·(C·S_prev^T) (K=128) + D_h·x
// Grid 4096, 256 thr (4 waves; wave w owns i-rows [16w,16w+16)).
// ---------------------------------------------------------------------------
__global__ __launch_bounds__(256) void ssd_output(
    const u16* __restrict__ xc, const float* __restrict__ dtb,
    const float* __restrict__ A_log, const float* __restrict__ Dvec,
    const u16* __restrict__ Sg,    // [bh][c][p][n] (T buffer after pass 2)
    u16* __restrict__ y)
{
    const int bid = blockIdx.x;
    const int b = bid >> 11, h = (bid >> 5) & 63, c = bid & 31;
    const int t0 = c * QCH;
    const int tid = threadIdx.x;
    const int wave = tid >> 6, lane = tid & 63;
    const int lr = lane & 15, lq = lane >> 4;

    __shared__ __align__(16) u16 C_lds[64][136];
    __shared__ __align__(16) u16 B_lds[64][136];
    __shared__ __align__(16) u16 S_lds[64][136];
    __shared__ __align__(16) u16 P_lds[64][72];
    __shared__ __align__(16) u16 XT[64][72];
    __shared__ float cumL[QCH], dtsL[QCH], escL[QCH];

    const u16* xg = xc + (size_t)b * LSEQ * CONV_DIM;

    if (tid < 64) {
        float dtv = dtb[((size_t)b * LSEQ + t0 + tid) * HEADS + h];
        float a = -dtv * expf(A_log[h]);
        float s = a;
        #pragma unroll
        for (int off = 1; off < 64; off <<= 1) {
            float o = __shfl_up(s, off, 64);
            if (tid >= off) s += o;
        }
        cumL[tid] = s;
        dtsL[tid] = dtv;
        escL[tid] = expf(s);
    }
    // stage C, B (row-major [j][n]) and S_prev (row-major [p][n]) as b128 copies
    #pragma unroll
    for (int r4 = 0; r4 < 4; ++r4) {
        int idx4 = tid + 256 * r4;
        int j = idx4 >> 4, c8 = (idx4 & 15) * 8;
        *(uint4*)&B_lds[j][c8] = *(const uint4*)(xg + (size_t)(t0 + j) * CONV_DIM + INTER + c8);
        *(uint4*)&C_lds[j][c8] = *(const uint4*)(xg + (size_t)(t0 + j) * CONV_DIM + INTER + NSTATE + c8);
        *(uint4*)&S_lds[j][c8] = *(const uint4*)(Sg + ((((size_t)(b * 64 + h)) * NCHUNK + c) * 64 + j) * 128 + c8);
    }
    // X^T: [p][j]
    #pragma unroll
    for (int r = 0; r < 16; ++r) {
        int idx = tid + 256 * r, j = idx >> 6, p = idx & 63;
        XT[p][j] = xg[(size_t)(t0 + j) * CONV_DIM + h * 64 + p];
    }
    __syncthreads();

    // G = C·B^T
    f32x4 accG[4];
    #pragma unroll
    for (int i = 0; i < 4; ++i) accG[i] = (f32x4)0.f;
    #pragma unroll
    for (int k0 = 0; k0 < NSTATE; k0 += 32) {
        short8 af = *(const short8*)&C_lds[wave * 16 + lr][k0 + lq * 8];
        #pragma unroll
        for (int jt = 0; jt < 4; ++jt) {
            short8 bfr = *(const short8*)&B_lds[jt * 16 + lr][k0 + lq * 8];
            accG[jt] = __builtin_amdgcn_mfma_f32_16x16x32_bf16(af, bfr, accG[jt], 0, 0, 0);
        }
    }
    // P = G ∘ M
    #pragma unroll
    for (int jt = 0; jt < 4; ++jt)
        #pragma unroll
        for (int r = 0; r < 4; ++r) {
            int ii = wave * 16 + lq * 4 + r;
            int jj = jt * 16 + lr;
            float v = (jj <= ii)
                ? accG[jt][r] * dtsL[jj] * expf(cumL[ii] - cumL[jj]) : 0.f;
            P_lds[ii][jj] = f2bf(v);
        }
    __syncthreads();

    // Y1 = P·X ; Y2 = C·S_prev^T
    f32x4 accY[4], accZ[4];
    #pragma unroll
    for (int i = 0; i < 4; ++i) { accY[i] = (f32x4)0.f; accZ[i] = (f32x4)0.f; }
    #pragma unroll
    for (int k0 = 0; k0 < QCH; k0 += 32) {
        short8 af = *(const short8*)&P_lds[wave * 16 + lr][k0 + lq * 8];
        #pragma unroll
        for (int pt = 0; pt < 4; ++pt) {
            short8 bfr = *(const short8*)&XT[pt * 16 + lr][k0 + lq * 8];
            accY[pt] = __builtin_amdgcn_mfma_f32_16x16x32_bf16(af, bfr, accY[pt], 0, 0, 0);
        }
    }
    #pragma unroll
    for (int k0 = 0; k0 < NSTATE; k0 += 32) {
        short8 af = *(const short8*)&C_lds[wave * 16 + lr][k0 + lq * 8];
        #pragma unroll
        for (int pt = 0; pt < 4; ++pt) {
            short8 bfr = *(const short8*)&S_lds[pt * 16 + lr][k0 + lq * 8];
            accZ[pt] = __builtin_amdgcn_mfma_f32_16x16x32_bf16(af, bfr, accZ[pt], 0, 0, 0);
        }
    }

    const float Dh = Dvec[h];
    u16* yg = y + ((size_t)b * LSEQ + t0) * INTER + h * 64;
    #pragma unroll
    for (int pt = 0; pt < 4; ++pt)
        #pragma unroll
        for (int r = 0; r < 4; ++r) {
            int ii = wave * 16 + lq * 4 + r;
            int pp = pt * 16 + lr;
            float xv = bf2f(XT[pp][ii]);
            float o = accY[pt][r] + escL[ii] * accZ[pt][r] + Dh * xv;
            yg[(size_t)ii * INTER + pp] = f2bf(o);
        }
}

// ---------------------------------------------------------------------------
// Gated RMSNorm (G=1). y bf16, gate bf16; normed bf16 written in-place.
// ---------------------------------------------------------------------------
__global__ __launch_bounds__(256) void norm_kernel(
    const u16* __restrict__ y, u16* __restrict__ gate,
    const float* __restrict__ w)
{
    const int row = blockIdx.x;
    const u16* yr = y    + (size_t)row * INTER;
    u16*       gr = gate + (size_t)row * INTER;
    const int tid = threadIdx.x;

    float v[16];
    float ss = 0.f;
    #pragma unroll
    for (int i = 0; i < 16; ++i) {
        int idx = tid + i * 256;
        float hv = bf2f(yr[idx]);
        float g  = bf2f(gr[idx]);
        float val = hv * (g / (1.f + expf(-g)));
        v[i] = val;
        ss = fmaf(val, val, ss);
    }
    #pragma unroll
    for (int o = 32; o > 0; o >>= 1) ss += __shfl_xor(ss, o);
    __shared__ float part[4];
    if ((tid & 63) == 0) part[tid >> 6] = ss;
    __syncthreads();
    float tot  = part[0] + part[1] + part[2] + part[3];
    float rinv = rsqrtf(tot * (1.f / INTER) + EPS);
    #pragma unroll
    for (int i = 0; i < 16; ++i) {
        int idx = tid + i * 256;
        gr[idx] = f2bf(w[idx] * v[i] * rinv);
    }
}

// ---------------------------------------------------------------------------
extern "C" void kernel_launch(void* const* d_in, const int* in_sizes, int n_in,
                              void* d_out, int out_size, void* d_ws, size_t ws_size,
                              hipStream_t stream)
{
    const float* hs      = (const float*)d_in[0];
    const float* W_z     = (const float*)d_in[1];
    const float* W_xBC   = (const float*)d_in[2];
    const float* W_dt    = (const float*)d_in[3];
    const float* conv_w  = (const float*)d_in[4];
    const float* conv_b  = (const float*)d_in[5];
    const float* dt_bias = (const float*)d_in[6];
    const float* A_log   = (const float*)d_in[7];
    const float* Dv      = (const float*)d_in[8];
    const float* norm_w  = (const float*)d_in[9];
    const float* W_out   = (const float*)d_in[10];
    float* out = (float*)d_out;
    char*  w8  = (char*)d_ws;

    // workspace layout (bytes); T aliases hs_bf/Wt_z/Wt_xc (dead before pass1)
    u16* hs_bf  = (u16*)(w8 + 0);            // 16,777,216
    u16* Wt_z   = (u16*)(w8 + 16777216);     // 16,777,216
    u16* Wt_xc  = (u16*)(w8 + 33554432);     // 18,350,080  (ends 51,904,512)
    u16* Tbuf   = (u16*)(w8 + 0);            // 67,108,864  (alias; pass1..pass3)
    u16* Wt_out = (u16*)(w8 + 67108864);     // 16,777,216
    u16* gate   = (u16*)(w8 + 83886080);     // 33,554,432
    u16* xpre   = (u16*)(w8 + 117440512);    // 36,700,160  (y aliases here)
    u16* xconv  = (u16*)(w8 + 154140672);    // 35,651,584
    float* dtb  = (float*)(w8 + 189792256);  // 1,048,576
    float* dcq  = (float*)(w8 + 190840832);  // 16,384      (total 190,857,216)
    u16* yb = xpre;

    const int M = B_SZ * LSEQ;               // 4096

    cvt_f32_bf16<<<(M * DMODEL / 4 + 255) / 256, 256, 0, stream>>>(hs, hs_bf, M * DMODEL / 4);
    tr_f32_bf16<<<dim3(INTER / 64,    DMODEL / 64), 256, 0, stream>>>(W_z,   Wt_z,  DMODEL, INTER);
    tr_f32_bf16<<<dim3(CONV_DIM / 64, DMODEL / 64), 256, 0, stream>>>(W_xBC, Wt_xc, DMODEL, CONV_DIM);
    tr_f32_bf16<<<dim3(1,             DMODEL / 64), 256, 0, stream>>>(W_dt,  Wt_xc + (size_t)CONV_DIM * DMODEL, DMODEL, 64);
    hipMemsetAsync(Wt_xc + (size_t)(CONV_DIM + 64) * DMODEL, 0, (size_t)64 * DMODEL * 2, stream);
    tr_f32_bf16<<<dim3(DMODEL / 64,   INTER / 64),  256, 0, stream>>>(W_out, Wt_out, INTER, DMODEL);

    gemm_nt<1><<<dim3(INTER / 128, M / 128), 256, 0, stream>>>(hs_bf, Wt_z,  (void*)gate, M, INTER, DMODEL);
    gemm_nt<1><<<dim3(XCOLS / 128, M / 128), 256, 0, stream>>>(hs_bf, Wt_xc, (void*)xpre, M, XCOLS, DMODEL);

    dt_kernel<<<(M * HEADS + 255) / 256, 256, 0, stream>>>(xpre, dtb, dt_bias, M * HEADS);
    conv_kernel<<<dim3(CONV_DIM / 256, M), 256, 0, stream>>>(xpre, conv_w, conv_b, xconv);

    // SSD scan replacement
    ssd_chunk_state<<<B_SZ * HEADS * NCHUNK, 256, 0, stream>>>(xconv, dtb, A_log, Tbuf, dcq);
    ssd_state_scan<<<B_SZ * HEADS, 256, 0, stream>>>(Tbuf, dcq);
    ssd_output<<<B_SZ * HEADS * NCHUNK, 256, 0, stream>>>(xconv, dtb, A_log, Dv, Tbuf, yb);

    norm_kernel<<<M, 256, 0, stream>>>(yb, gate, norm_w);

    gemm_nt<0><<<dim3(DMODEL / 128, M / 128), 256, 0, stream>>>(gate, Wt_out, (void*)out, M, DMODEL, INTER);
}

// Round 5
// 632.253 us; speedup vs baseline: 10.4322x; 1.1070x over previous
//
#include <hip/hip_runtime.h>
#include <hip/hip_bf16.h>
#include <math.h>

typedef unsigned short u16;
typedef unsigned int   u32;
typedef __attribute__((ext_vector_type(8))) short short8;
typedef __attribute__((ext_vector_type(4))) float f32x4;

#define B_SZ     2
#define LSEQ     2048
#define DMODEL   2048
#define INTER    4096
#define HEADS    64
#define NSTATE   128
#define CONV_DIM 4352            /* INTER + 2*128 */
#define XSTR     8576            /* fused xall row stride: 4096 gate + 4480 xBC/dt */
#define NFUSE    8576
#define EPS      1e-5f
#define QCH      64              /* SSD chunk length */
#define NCHUNK   (LSEQ / QCH)    /* 32 */

__device__ __forceinline__ float bf2f(u16 u) {
    u32 v = ((u32)u) << 16;
    return __builtin_bit_cast(float, v);
}
__device__ __forceinline__ u16 f2bf(float x) {
    __hip_bfloat16 h = __float2bfloat16(x);   // RNE
    return __builtin_bit_cast(u16, h);
}
__device__ __forceinline__ u32 pack2(float lo, float hi) {
    return (u32)f2bf(lo) | ((u32)f2bf(hi) << 16);
}
__device__ __forceinline__ void gl2lds16(const void* g, void* l) {
    __builtin_amdgcn_global_load_lds(
        (const __attribute__((address_space(1))) u32*)g,
        (__attribute__((address_space(3))) u32*)l, 16, 0, 0);
}

// ---------------------------------------------------------------------------
// fp32 -> bf16 elementwise (n4 = count/4)
// ---------------------------------------------------------------------------
__global__ __launch_bounds__(256) void cvt_f32_bf16(
    const float* __restrict__ in, u16* __restrict__ out, int n4)
{
    int i = blockIdx.x * 256 + threadIdx.x;
    if (i >= n4) return;
    float4 v = ((const float4*)in)[i];
    ushort4 o;
    o.x = f2bf(v.x); o.y = f2bf(v.y); o.z = f2bf(v.z); o.w = f2bf(v.w);
    ((ushort4*)out)[i] = o;
}

// ---------------------------------------------------------------------------
// Transpose + convert: in fp32 [R][C] -> out bf16 [C][R]. R,C multiples of 64.
// ---------------------------------------------------------------------------
__global__ __launch_bounds__(256) void tr_f32_bf16(
    const float* __restrict__ in, u16* __restrict__ out, int R, int C)
{
    __shared__ u16 tile[64][68];
    const int r0 = blockIdx.y * 64, c0 = blockIdx.x * 64;
    const int tr = threadIdx.x >> 4, tc = (threadIdx.x & 15) * 4;
    #pragma unroll
    for (int i = 0; i < 4; ++i) {
        int r = tr + i * 16;
        float4 v = *(const float4*)(in + (size_t)(r0 + r) * C + c0 + tc);
        tile[r][tc + 0] = f2bf(v.x);
        tile[r][tc + 1] = f2bf(v.y);
        tile[r][tc + 2] = f2bf(v.z);
        tile[r][tc + 3] = f2bf(v.w);
    }
    __syncthreads();
    #pragma unroll
    for (int i = 0; i < 4; ++i) {
        int oc = tr + i * 16;
        ushort4 o;
        o.x = tile[tc + 0][oc];
        o.y = tile[tc + 1][oc];
        o.z = tile[tc + 2][oc];
        o.w = tile[tc + 3][oc];
        *(ushort4*)(out + (size_t)(c0 + oc) * R + r0 + tc) = o;
    }
}

// ---------------------------------------------------------------------------
// bf16 MFMA GEMM, NT form: C[M,N] = A[M,K](lda) @ Bt[N,K]^T.
// 128x128 tile, BK=64, XOR-swizzled LDS (conflict-free b128 fragment reads),
// paired-lane packed epilogue. M%128==0, N%128==0, K%64==0.
// ---------------------------------------------------------------------------
template<int OUT_BF16>
__global__ __launch_bounds__(256) void gemm_nt(
    const u16* __restrict__ A, const u16* __restrict__ Bt,
    void* __restrict__ Co, int M, int N, int K, int lda)
{
    __shared__ __align__(16) u16 As[128 * 64];   // 16 KB, row = 128 B
    __shared__ __align__(16) u16 Bs[128 * 64];
    const int tid  = threadIdx.x;
    const int wave = tid >> 6, lane = tid & 63;
    const int m0 = blockIdx.y * 128, n0 = blockIdx.x * 128;
    const int wm = (wave >> 1) * 64, wn = (wave & 1) * 64;

    // staging: wave w covers rows [32w, 32w+32), 4 calls of 8 rows each.
    // lane l -> row sub l>>3, slot-colblock l&7; SOURCE colblock (l&7)^(l>>3)
    // so that LDS slot (row, s) holds global colblock s ^ (row&7).
    const int l3  = lane >> 3, lcb = lane & 7;
    const int swrow = wave * 32;
    const int scb8  = (lcb ^ l3) << 3;          // swizzled source col (u16)

    f32x4 acc[4][4];
    #pragma unroll
    for (int i = 0; i < 4; ++i)
        #pragma unroll
        for (int j = 0; j < 4; ++j) acc[i][j] = (f32x4)0.f;

    const int lr = lane & 15, lq = lane >> 4;

    for (int k0 = 0; k0 < K; k0 += 64) {
        __syncthreads();
        #pragma unroll
        for (int q = 0; q < 4; ++q) {
            int row = swrow + q * 8 + l3;
            gl2lds16(A  + (size_t)(m0 + row) * lda + scb8 + k0, As + (swrow + q * 8) * 64);
            gl2lds16(Bt + (size_t)(n0 + row) * K   + scb8 + k0, Bs + (swrow + q * 8) * 64);
        }
        __syncthreads();

        #pragma unroll
        for (int kk = 0; kk < 2; ++kk) {
            short8 af[4], bfr[4];
            #pragma unroll
            for (int i = 0; i < 4; ++i) {
                int row = wm + i * 16 + lr;
                int slot = (kk * 4 + lq) ^ (lr & 7);
                af[i] = *(const short8*)(As + row * 64 + slot * 8);
            }
            #pragma unroll
            for (int j = 0; j < 4; ++j) {
                int row = wn + j * 16 + lr;
                int slot = (kk * 4 + lq) ^ (lr & 7);
                bfr[j] = *(const short8*)(Bs + row * 64 + slot * 8);
            }
            #pragma unroll
            for (int i = 0; i < 4; ++i)
                #pragma unroll
                for (int j = 0; j < 4; ++j)
                    acc[i][j] = __builtin_amdgcn_mfma_f32_16x16x32_bf16(
                        af[i], bfr[j], acc[i][j], 0, 0, 0);
        }
    }

    // Epilogue: C/D layout col=lr, row=lq*4+r. Pair lanes (lr, lr^1) to pack
    // two adjacent cols; even lane stores rows lq*4+{0,1}, odd rows +{2,3}.
    const int odd  = lr & 1;
    #pragma unroll
    for (int i = 0; i < 4; ++i)
        #pragma unroll
        for (int j = 0; j < 4; ++j) {
            float v0 = acc[i][j][0], v1 = acc[i][j][1];
            float v2 = acc[i][j][2], v3 = acc[i][j][3];
            float n0v = __shfl_xor(v0, 1), n1v = __shfl_xor(v1, 1);
            float n2v = __shfl_xor(v2, 1), n3v = __shfl_xor(v3, 1);
            int colb  = n0 + wn + j * 16 + (lr & ~1);
            int rbase = m0 + wm + i * 16 + lq * 4 + odd * 2;
            if (OUT_BF16) {
                u32 w0 = odd ? pack2(n2v, v2) : pack2(v0, n0v);
                u32 w1 = odd ? pack2(n3v, v3) : pack2(v1, n1v);
                *(u32*)((u16*)Co + (size_t)rbase * N + colb) = w0;
                *(u32*)((u16*)Co + (size_t)(rbase + 1) * N + colb) = w1;
            } else {
                float2 f0 = odd ? make_float2(n2v, v2) : make_float2(v0, n0v);
                float2 f1 = odd ? make_float2(n3v, v3) : make_float2(v1, n1v);
                *(float2*)((float*)Co + (size_t)rbase * N + colb) = f0;
                *(float2*)((float*)Co + (size_t)(rbase + 1) * N + colb) = f1;
            }
        }
}

// ---------------------------------------------------------------------------
// dt = softplus(dt_mm + bias). dt_mm read from xall bf16 cols [8448,8512).
// ---------------------------------------------------------------------------
__global__ void dt_kernel(const u16* __restrict__ xall,
                          float* __restrict__ dtb,
                          const float* __restrict__ dt_bias, int n)
{
    int i = blockIdx.x * 256 + threadIdx.x;
    if (i >= n) return;
    int h = i & 63, row = i >> 6;
    float x = bf2f(xall[(size_t)row * XSTR + INTER + CONV_DIM + h]) + dt_bias[h];
    dtb[i] = (x < 10.f) ? log1pf(expf(x)) : x;
}

// ---------------------------------------------------------------------------
// Causal depthwise conv1d (K=4) + bias + silu. Input = xall cols [4096,8448).
// ---------------------------------------------------------------------------
__global__ void conv_kernel(const u16* __restrict__ xall,
                            const float* __restrict__ cw,
                            const float* __restrict__ cb,
                            u16* __restrict__ xout)
{
    int c  = blockIdx.x * 256 + threadIdx.x;   // 0..4351
    int bt = blockIdx.y;
    int t  = bt & (LSEQ - 1);
    const u16* xi = xall + (size_t)bt * XSTR + INTER + c;
    float4 w = *(const float4*)(cw + (size_t)c * 4);
    float acc = cb[c];
    acc = fmaf(bf2f(xi[0]), w.w, acc);
    if (t >= 1) acc = fmaf(bf2f(*(xi - XSTR)),     w.z, acc);
    if (t >= 2) acc = fmaf(bf2f(*(xi - 2 * XSTR)), w.y, acc);
    if (t >= 3) acc = fmaf(bf2f(*(xi - 3 * XSTR)), w.x, acc);
    xout[(size_t)bt * CONV_DIM + c] = f2bf(acc / (1.f + expf(-acc)));
}

// ---------------------------------------------------------------------------
// SSD pass 1: T[p][n] = sum_j Xw[j][p] B[j][n], Xw = dt_j e^{cumQ-cum_j} x.
// ---------------------------------------------------------------------------
__global__ __launch_bounds__(256) void ssd_chunk_state(
    const u16* __restrict__ xc, const float* __restrict__ dtb,
    const float* __restrict__ A_log,
    u16* __restrict__ Tg, float* __restrict__ decayQ)
{
    const int bid = blockIdx.x;
    const int b = bid >> 11, h = (bid >> 5) & 63, c = bid & 31;
    const int t0 = c * QCH;
    const int tid = threadIdx.x;
    const int wave = tid >> 6, lane = tid & 63;
    const int lr = lane & 15, lq = lane >> 4;

    __shared__ __align__(16) u16 BT[128][72];   // B^T: [n][j]
    __shared__ __align__(16) u16 XwT[64][72];   // Xw^T: [p][j]
    __shared__ float sclL[QCH];

    const u16* xg = xc + (size_t)b * LSEQ * CONV_DIM;

    if (tid < 64) {
        float dtv = dtb[((size_t)b * LSEQ + t0 + tid) * HEADS + h];
        float a = -dtv * expf(A_log[h]);
        float s = a;
        #pragma unroll
        for (int off = 1; off < 64; off <<= 1) {
            float o = __shfl_up(s, off, 64);
            if (tid >= off) s += o;
        }
        float cq = __shfl(s, 63, 64);
        sclL[tid] = dtv * expf(cq - s);
        if (tid == 0) decayQ[((b * 64 + h) << 5) + c] = expf(cq);
    }
    __syncthreads();

    #pragma unroll
    for (int r = 0; r < 16; ++r) {
        int idx = tid + 256 * r, j = idx >> 6, p = idx & 63;
        float v = bf2f(xg[(size_t)(t0 + j) * CONV_DIM + h * 64 + p]);
        XwT[p][j] = f2bf(v * sclL[j]);
    }
    #pragma unroll
    for (int r = 0; r < 32; ++r) {
        int idx = tid + 256 * r, j = idx >> 7, n = idx & 127;
        BT[n][j] = xg[(size_t)(t0 + j) * CONV_DIM + INTER + n];
    }
    __syncthreads();

    f32x4 acc[8];
    #pragma unroll
    for (int i = 0; i < 8; ++i) acc[i] = (f32x4)0.f;
    #pragma unroll
    for (int k0 = 0; k0 < QCH; k0 += 32) {
        short8 af = *(const short8*)&XwT[wave * 16 + lr][k0 + lq * 8];
        #pragma unroll
        for (int nt = 0; nt < 8; ++nt) {
            short8 bfr = *(const short8*)&BT[nt * 16 + lr][k0 + lq * 8];
            acc[nt] = __builtin_amdgcn_mfma_f32_16x16x32_bf16(af, bfr, acc[nt], 0, 0, 0);
        }
    }
    u16* To = Tg + ((((size_t)(b * 64 + h)) * NCHUNK + c) * 64) * 128;
    #pragma unroll
    for (int nt = 0; nt < 8; ++nt)
        #pragma unroll
        for (int r = 0; r < 4; ++r)
            To[(wave * 16 + lq * 4 + r) * 128 + nt * 16 + lr] = f2bf(acc[nt][r]);
}

// ---------------------------------------------------------------------------
// SSD pass 2: sequential recurrence over chunk states (in-place).
// ---------------------------------------------------------------------------
__global__ __launch_bounds__(256) void ssd_state_scan(
    u16* __restrict__ Tg, const float* __restrict__ decayQ)
{
    const int bh = blockIdx.x, tid = threadIdx.x;
    const int p = tid >> 2, nb = (tid & 3) * 32;
    float S[32];
    #pragma unroll
    for (int m = 0; m < 32; ++m) S[m] = 0.f;

    for (int c = 0; c < NCHUNK; ++c) {
        u16* base = Tg + ((((size_t)bh * NCHUNK + c) * 64 + p) * 128) + nb;
        uint4 tv[4];
        #pragma unroll
        for (int k = 0; k < 4; ++k) tv[k] = *(const uint4*)(base + k * 8);
        #pragma unroll
        for (int k = 0; k < 4; ++k) {
            uint4 sv;
            sv.x = pack2(S[k*8+0], S[k*8+1]);
            sv.y = pack2(S[k*8+2], S[k*8+3]);
            sv.z = pack2(S[k*8+4], S[k*8+5]);
            sv.w = pack2(S[k*8+6], S[k*8+7]);
            *(uint4*)(base + k * 8) = sv;
        }
        float dq = decayQ[(bh << 5) + c];
        #pragma unroll
        for (int k = 0; k < 4; ++k) {
            const u32* w = (const u32*)&tv[k];
            #pragma unroll
            for (int e = 0; e < 4; ++e) {
                S[k*8 + e*2]     = fmaf(dq, S[k*8 + e*2],     bf2f((u16)(w[e] & 0xffffu)));
                S[k*8 + e*2 + 1] = fmaf(dq, S[k*8 + e*2 + 1], bf2f((u16)(w[e] >> 16)));
            }
        }
    }
}

// ---------------------------------------------------------------------------
// SSD pass 3: Y = (C·B^T ∘ M)·X + diag(e^{cum})·(C·S_prev^T) + D·x.
// y written strided (YSTR) into the dead xBC region of xall.
// ---------------------------------------------------------------------------
__global__ __launch_bounds__(256) void ssd_output(
    const u16* __restrict__ xc, const float* __restrict__ dtb,
    const float* __restrict__ A_log, const float* __restrict__ Dvec,
    const u16* __restrict__ Sg,
    u16* __restrict__ y)           // base xall+4096, row stride XSTR
{
    const int bid = blockIdx.x;
    const int b = bid >> 11, h = (bid >> 5) & 63, c = bid & 31;
    const int t0 = c * QCH;
    const int tid = threadIdx.x;
    const int wave = tid >> 6, lane = tid & 63;
    const int lr = lane & 15, lq = lane >> 4;

    __shared__ __align__(16) u16 C_lds[64][136];
    __shared__ __align__(16) u16 B_lds[64][136];
    __shared__ __align__(16) u16 S_lds[64][136];
    __shared__ __align__(16) u16 P_lds[64][72];
    __shared__ __align__(16) u16 XT[64][72];
    __shared__ float cumL[QCH], dtsL[QCH], escL[QCH];

    const u16* xg = xc + (size_t)b * LSEQ * CONV_DIM;

    if (tid < 64) {
        float dtv = dtb[((size_t)b * LSEQ + t0 + tid) * HEADS + h];
        float a = -dtv * expf(A_log[h]);
        float s = a;
        #pragma unroll
        for (int off = 1; off < 64; off <<= 1) {
            float o = __shfl_up(s, off, 64);
            if (tid >= off) s += o;
        }
        cumL[tid] = s;
        dtsL[tid] = dtv;
        escL[tid] = expf(s);
    }
    #pragma unroll
    for (int r4 = 0; r4 < 4; ++r4) {
        int idx4 = tid + 256 * r4;
        int j = idx4 >> 4, c8 = (idx4 & 15) * 8;
        *(uint4*)&B_lds[j][c8] = *(const uint4*)(xg + (size_t)(t0 + j) * CONV_DIM + INTER + c8);
        *(uint4*)&C_lds[j][c8] = *(const uint4*)(xg + (size_t)(t0 + j) * CONV_DIM + INTER + NSTATE + c8);
        *(uint4*)&S_lds[j][c8] = *(const uint4*)(Sg + ((((size_t)(b * 64 + h)) * NCHUNK + c) * 64 + j) * 128 + c8);
    }
    #pragma unroll
    for (int r = 0; r < 16; ++r) {
        int idx = tid + 256 * r, j = idx >> 6, p = idx & 63;
        XT[p][j] = xg[(size_t)(t0 + j) * CONV_DIM + h * 64 + p];
    }
    __syncthreads();

    f32x4 accG[4];
    #pragma unroll
    for (int i = 0; i < 4; ++i) accG[i] = (f32x4)0.f;
    #pragma unroll
    for (int k0 = 0; k0 < NSTATE; k0 += 32) {
        short8 af = *(const short8*)&C_lds[wave * 16 + lr][k0 + lq * 8];
        #pragma unroll
        for (int jt = 0; jt < 4; ++jt) {
            short8 bfr = *(const short8*)&B_lds[jt * 16 + lr][k0 + lq * 8];
            accG[jt] = __builtin_amdgcn_mfma_f32_16x16x32_bf16(af, bfr, accG[jt], 0, 0, 0);
        }
    }
    #pragma unroll
    for (int jt = 0; jt < 4; ++jt)
        #pragma unroll
        for (int r = 0; r < 4; ++r) {
            int ii = wave * 16 + lq * 4 + r;
            int jj = jt * 16 + lr;
            float v = (jj <= ii)
                ? accG[jt][r] * dtsL[jj] * expf(cumL[ii] - cumL[jj]) : 0.f;
            P_lds[ii][jj] = f2bf(v);
        }
    __syncthreads();

    f32x4 accY[4], accZ[4];
    #pragma unroll
    for (int i = 0; i < 4; ++i) { accY[i] = (f32x4)0.f; accZ[i] = (f32x4)0.f; }
    #pragma unroll
    for (int k0 = 0; k0 < QCH; k0 += 32) {
        short8 af = *(const short8*)&P_lds[wave * 16 + lr][k0 + lq * 8];
        #pragma unroll
        for (int pt = 0; pt < 4; ++pt) {
            short8 bfr = *(const short8*)&XT[pt * 16 + lr][k0 + lq * 8];
            accY[pt] = __builtin_amdgcn_mfma_f32_16x16x32_bf16(af, bfr, accY[pt], 0, 0, 0);
        }
    }
    #pragma unroll
    for (int k0 = 0; k0 < NSTATE; k0 += 32) {
        short8 af = *(const short8*)&C_lds[wave * 16 + lr][k0 + lq * 8];
        #pragma unroll
        for (int pt = 0; pt < 4; ++pt) {
            short8 bfr = *(const short8*)&S_lds[pt * 16 + lr][k0 + lq * 8];
            accZ[pt] = __builtin_amdgcn_mfma_f32_16x16x32_bf16(af, bfr, accZ[pt], 0, 0, 0);
        }
    }

    const float Dh = Dvec[h];
    u16* yg = y + ((size_t)b * LSEQ + t0) * XSTR + h * 64;
    #pragma unroll
    for (int pt = 0; pt < 4; ++pt)
        #pragma unroll
        for (int r = 0; r < 4; ++r) {
            int ii = wave * 16 + lq * 4 + r;
            int pp = pt * 16 + lr;
            float xv = bf2f(XT[pp][ii]);
            float o = accY[pt][r] + escL[ii] * accZ[pt][r] + Dh * xv;
            yg[(size_t)ii * XSTR + pp] = f2bf(o);
        }
}

// ---------------------------------------------------------------------------
// Gated RMSNorm (G=1). y = xall cols [4096,8192), gate = cols [0,4096);
// normed bf16 written in-place over gate. Row stride XSTR.
// ---------------------------------------------------------------------------
__global__ __launch_bounds__(256) void norm_kernel(
    u16* __restrict__ xall, const float* __restrict__ w)
{
    const int row = blockIdx.x;
    const u16* yr = xall + (size_t)row * XSTR + INTER;
    u16*       gr = xall + (size_t)row * XSTR;
    const int tid = threadIdx.x;

    float v[16];
    float ss = 0.f;
    #pragma unroll
    for (int i = 0; i < 16; ++i) {
        int idx = tid + i * 256;
        float hv = bf2f(yr[idx]);
        float g  = bf2f(gr[idx]);
        float val = hv * (g / (1.f + expf(-g)));
        v[i] = val;
        ss = fmaf(val, val, ss);
    }
    #pragma unroll
    for (int o = 32; o > 0; o >>= 1) ss += __shfl_xor(ss, o);
    __shared__ float part[4];
    if ((tid & 63) == 0) part[tid >> 6] = ss;
    __syncthreads();
    float tot  = part[0] + part[1] + part[2] + part[3];
    float rinv = rsqrtf(tot * (1.f / INTER) + EPS);
    #pragma unroll
    for (int i = 0; i < 16; ++i) {
        int idx = tid + i * 256;
        gr[idx] = f2bf(w[idx] * v[i] * rinv);
    }
}

// ---------------------------------------------------------------------------
extern "C" void kernel_launch(void* const* d_in, const int* in_sizes, int n_in,
                              void* d_out, int out_size, void* d_ws, size_t ws_size,
                              hipStream_t stream)
{
    const float* hs      = (const float*)d_in[0];
    const float* W_z     = (const float*)d_in[1];
    const float* W_xBC   = (const float*)d_in[2];
    const float* W_dt    = (const float*)d_in[3];
    const float* conv_w  = (const float*)d_in[4];
    const float* conv_b  = (const float*)d_in[5];
    const float* dt_bias = (const float*)d_in[6];
    const float* A_log   = (const float*)d_in[7];
    const float* Dv      = (const float*)d_in[8];
    const float* norm_w  = (const float*)d_in[9];
    const float* W_out   = (const float*)d_in[10];
    float* out = (float*)d_out;
    char*  w8  = (char*)d_ws;

    // workspace (bytes):
    u16* hs_bf  = (u16*)(w8 + 0);            // 16,777,216
    u16* Wt_all = (u16*)(w8 + 16777216);     // 8576*2048*2 = 35,127,296 (ends 51,904,512)
    u16* Tbuf   = (u16*)(w8 + 0);            // 67,108,864 (alias hs_bf+Wt_all; SSD phase)
    u16* Wt_out = (u16*)(w8 + 67108864);     // 16,777,216
    u16* xall   = (u16*)(w8 + 83886080);     // 4096*8576*2 = 70,254,592 (ends 154,140,672)
    u16* xconv  = (u16*)(w8 + 154140672);    // 35,651,584
    float* dtb  = (float*)(w8 + 189792256);  // 1,048,576
    float* dcq  = (float*)(w8 + 190840832);  // 16,384 (total 190,857,216)

    const int M = B_SZ * LSEQ;               // 4096

    cvt_f32_bf16<<<(M * DMODEL / 4 + 255) / 256, 256, 0, stream>>>(hs, hs_bf, M * DMODEL / 4);
    // Wt_all rows: [0,4096) = W_z^T, [4096,8448) = W_xBC^T, [8448,8512) = W_dt^T, rest pad
    tr_f32_bf16<<<dim3(INTER / 64,    DMODEL / 64), 256, 0, stream>>>(W_z,   Wt_all, DMODEL, INTER);
    tr_f32_bf16<<<dim3(CONV_DIM / 64, DMODEL / 64), 256, 0, stream>>>(W_xBC, Wt_all + (size_t)INTER * DMODEL, DMODEL, CONV_DIM);
    tr_f32_bf16<<<dim3(1,             DMODEL / 64), 256, 0, stream>>>(W_dt,  Wt_all + (size_t)(INTER + CONV_DIM) * DMODEL, DMODEL, 64);
    hipMemsetAsync(Wt_all + (size_t)(INTER + CONV_DIM + 64) * DMODEL, 0, (size_t)64 * DMODEL * 2, stream);
    tr_f32_bf16<<<dim3(DMODEL / 64,   INTER / 64),  256, 0, stream>>>(W_out, Wt_out, INTER, DMODEL);

    // fused projection GEMM: [4096][8576] = gate | xBC | dt | pad
    gemm_nt<1><<<dim3(NFUSE / 128, M / 128), 256, 0, stream>>>(
        hs_bf, Wt_all, (void*)xall, M, NFUSE, DMODEL, DMODEL);

    dt_kernel<<<(M * HEADS + 255) / 256, 256, 0, stream>>>(xall, dtb, dt_bias, M * HEADS);
    conv_kernel<<<dim3(CONV_DIM / 256, M), 256, 0, stream>>>(xall, conv_w, conv_b, xconv);

    ssd_chunk_state<<<B_SZ * HEADS * NCHUNK, 256, 0, stream>>>(xconv, dtb, A_log, Tbuf, dcq);
    ssd_state_scan<<<B_SZ * HEADS, 256, 0, stream>>>(Tbuf, dcq);
    ssd_output<<<B_SZ * HEADS * NCHUNK, 256, 0, stream>>>(xconv, dtb, A_log, Dv, Tbuf, xall + INTER);

    norm_kernel<<<M, 256, 0, stream>>>(xall, norm_w);

    gemm_nt<0><<<dim3(DMODEL / 128, M / 128), 256, 0, stream>>>(
        xall, Wt_out, (void*)out, M, DMODEL, INTER, XSTR);
}